// Round 2
// baseline (1026.152 us; speedup 1.0000x reference)
//
#include <hip/hip_runtime.h>
#include <hip/hip_bf16.h>

// MoE block: H=2048, F=8192, E=8, top-2, T=512 tokens. All inputs fp32.
// Router -> per-expert token lists -> fused gated GEMM1 (W1,W3 -> h bf16)
// -> GEMM2 (W2 -> scaled atomic scatter into out).
// Round 2: coalesced staging (256B segments), cvt_pk conversion, 2-phase
// register prefetch. LDS layouts / MFMA fragment math identical to the
// numerically-verified round-1 kernel.

#define HDIM 2048
#define FDIM 8192
#define NEXP 8
#define NTOK 512
#define MAXT 512

typedef __attribute__((ext_vector_type(8))) short short8;
typedef __attribute__((ext_vector_type(4))) float f32x4;

__device__ __forceinline__ unsigned cvtpk(float lo, float hi) {
    unsigned r;
    asm("v_cvt_pk_bf16_f32 %0, %1, %2" : "=v"(r) : "v"(lo), "v"(hi));
    return r;
}
__device__ __forceinline__ unsigned f2bf1(float f) {
    unsigned u = __builtin_bit_cast(unsigned, f);
    return (u + 0x7FFFu + ((u >> 16) & 1u)) >> 16;
}

// LDS byte offsets with XOR swizzle (16B granularity) — verified round 1.
#define A_OFF(r, k) (((((r)*64) + (k)) * 2) ^ ((((r) & 7)) << 4))
#define B_OFF(n, k) (((((n)*64) + (k)) * 2) ^ ((((n) & 7)) << 4))

// ---------------------------------------------------------------- router
__global__ void moe_router(const float* __restrict__ x, const float* __restrict__ Wg,
                           int* __restrict__ counts, int* __restrict__ tok_id,
                           float* __restrict__ tok_w) {
    const int t = blockIdx.x;
    const int lane = threadIdx.x;
    const float* xr = x + (size_t)t * HDIM;
    float acc[8];
    #pragma unroll
    for (int e = 0; e < 8; ++e) acc[e] = 0.f;
    #pragma unroll 4
    for (int i = 0; i < HDIM / 64; ++i) {
        int h = lane + i * 64;
        float xv = xr[h];
        const float4* wr = (const float4*)(Wg + (size_t)h * 8);
        float4 wa = wr[0], wb = wr[1];
        acc[0] += xv * wa.x; acc[1] += xv * wa.y; acc[2] += xv * wa.z; acc[3] += xv * wa.w;
        acc[4] += xv * wb.x; acc[5] += xv * wb.y; acc[6] += xv * wb.z; acc[7] += xv * wb.w;
    }
    #pragma unroll
    for (int off = 32; off >= 1; off >>= 1) {
        #pragma unroll
        for (int e = 0; e < 8; ++e) acc[e] += __shfl_xor(acc[e], off);
    }
    if (lane == 0) {
        int e0 = 0;
        #pragma unroll
        for (int e = 1; e < 8; ++e) if (acc[e] > acc[e0]) e0 = e;
        int e1 = (e0 == 0) ? 1 : 0;
        #pragma unroll
        for (int e = 0; e < 8; ++e) if (e != e0 && acc[e] > acc[e1]) e1 = e;
        float w0 = 1.f / (1.f + __expf(acc[e1] - acc[e0]));
        float w1 = 1.f - w0;
        int s0 = atomicAdd(&counts[e0], 1);
        tok_id[e0 * MAXT + s0] = t; tok_w[e0 * MAXT + s0] = w0;
        int s1 = atomicAdd(&counts[e1], 1);
        tok_id[e1 * MAXT + s1] = t; tok_w[e1 * MAXT + s1] = w1;
    }
}

__global__ void moe_scan(const int* __restrict__ counts, int* __restrict__ offsets) {
    if (threadIdx.x == 0) {
        int a = 0;
        for (int e = 0; e < NEXP; ++e) { offsets[e] = a; a += counts[e]; }
    }
}

// ---------------------------------------------------------------- GEMM1
// h[slot, n] = relu(x W1)[slot, n] * (x W3)[slot, n], bf16 out.
// BM=128 x BN=64 x BK=64, 256 thr (waves 2x2), 2-phase reg prefetch.
__global__ __launch_bounds__(256, 2)
void moe_gemm1(const float* __restrict__ x, const float* __restrict__ W1,
               const float* __restrict__ W3, const int* __restrict__ counts,
               const int* __restrict__ offsets, const int* __restrict__ tok_id,
               unsigned short* __restrict__ hbuf) {
    const int nt = blockIdx.x, mt = blockIdx.y, e = blockIdx.z;
    const int cnt = counts[e];
    if (mt * 128 >= cnt) return;
    const int n0 = nt * 64;
    const int tid = threadIdx.x;

    __shared__ __align__(16) unsigned char sA[128 * 64 * 2];
    __shared__ __align__(16) unsigned char sB1[64 * 64 * 2];
    __shared__ __align__(16) unsigned char sB3[64 * 64 * 2];

    // A staging: 16 lanes/row, one float4 each; 8 row passes.
    // Wave instr = 4 rows x 256B contiguous.
    const int ar0 = tid >> 4;          // 0..15
    const int ak4 = (tid & 15) * 4;    // k offset
    const float* aptr[8];
    #pragma unroll
    for (int p = 0; p < 8; ++p) {
        int slot = mt * 128 + ar0 + 16 * p;
        int tok = tok_id[e * MAXT + (slot < cnt ? slot : cnt - 1)];
        aptr[p] = x + (size_t)tok * HDIM + ak4;
    }
    // B staging: thread covers rows kq4..kq4+3 x cols n4..n4+3 (one pass).
    // Wave instr = 4 rows x 256B contiguous.
    const int kq4 = (tid >> 4) * 4;    // 0..60
    const int n4 = (tid & 15) * 4;
    const size_t wstride = (size_t)HDIM * FDIM;
    const float* b1p = W1 + (size_t)e * wstride + (size_t)kq4 * FDIM + n0 + n4;
    const float* b3p = W3 + (size_t)e * wstride + (size_t)kq4 * FDIM + n0 + n4;

    const int w = tid >> 6, l = tid & 63;
    const int wr = (w >> 1) * 64, wc = (w & 1) * 32;
    const int lr = l & 15, lk = (l >> 4) * 8;

    f32x4 acc1[4][2], acc3[4][2];
    #pragma unroll
    for (int mi = 0; mi < 4; ++mi)
        #pragma unroll
        for (int ni = 0; ni < 2; ++ni) { acc1[mi][ni] = (f32x4)0.f; acc3[mi][ni] = (f32x4)0.f; }

    float4 areg[8], b1r[4], b3r[4];
    // prologue: load tile 0
    #pragma unroll
    for (int p = 0; p < 8; ++p) areg[p] = *(const float4*)(aptr[p]);
    #pragma unroll
    for (int r = 0; r < 4; ++r) {
        b1r[r] = *(const float4*)(b1p + (size_t)r * FDIM);
        b3r[r] = *(const float4*)(b3p + (size_t)r * FDIM);
    }

    for (int kt = 0; kt < HDIM / 64; ++kt) {
        // ---- cvt + LDS write (vmcnt wait inserted by compiler)
        #pragma unroll
        for (int p = 0; p < 8; ++p) {
            uint2 q;
            q.x = cvtpk(areg[p].x, areg[p].y);
            q.y = cvtpk(areg[p].z, areg[p].w);
            *(uint2*)&sA[A_OFF(ar0 + 16 * p, ak4)] = q;
        }
        {
            const float* f1 = (const float*)b1r;
            const float* f3 = (const float*)b3r;
            #pragma unroll
            for (int c = 0; c < 4; ++c) {
                uint2 q1, q3;
                q1.x = cvtpk(f1[c], f1[4 + c]);
                q1.y = cvtpk(f1[8 + c], f1[12 + c]);
                *(uint2*)&sB1[B_OFF(n4 + c, kq4)] = q1;
                q3.x = cvtpk(f3[c], f3[4 + c]);
                q3.y = cvtpk(f3[8 + c], f3[12 + c]);
                *(uint2*)&sB3[B_OFF(n4 + c, kq4)] = q3;
            }
        }
        __syncthreads();
        // ---- prefetch next tile into regs (overlaps with MFMA below)
        if (kt + 1 < HDIM / 64) {
            #pragma unroll
            for (int p = 0; p < 8; ++p)
                areg[p] = *(const float4*)(aptr[p] + (kt + 1) * 64);
            #pragma unroll
            for (int r = 0; r < 4; ++r) {
                b1r[r] = *(const float4*)(b1p + (size_t)((kt + 1) * 64 + r) * FDIM);
                b3r[r] = *(const float4*)(b3p + (size_t)((kt + 1) * 64 + r) * FDIM);
            }
        }
        // ---- MFMA
        #pragma unroll
        for (int ks = 0; ks < 2; ++ks) {
            const int kk = ks * 32 + lk;
            short8 a[4];
            #pragma unroll
            for (int mi = 0; mi < 4; ++mi)
                a[mi] = *(const short8*)&sA[A_OFF(wr + mi * 16 + lr, kk)];
            #pragma unroll
            for (int ni = 0; ni < 2; ++ni) {
                short8 b1 = *(const short8*)&sB1[B_OFF(wc + ni * 16 + lr, kk)];
                short8 b3 = *(const short8*)&sB3[B_OFF(wc + ni * 16 + lr, kk)];
                #pragma unroll
                for (int mi = 0; mi < 4; ++mi) {
                    acc1[mi][ni] = __builtin_amdgcn_mfma_f32_16x16x32_bf16(a[mi], b1, acc1[mi][ni], 0, 0, 0);
                    acc3[mi][ni] = __builtin_amdgcn_mfma_f32_16x16x32_bf16(a[mi], b3, acc3[mi][ni], 0, 0, 0);
                }
            }
        }
        __syncthreads();
    }
    // ---- epilogue: h = relu(h1)*h3 -> bf16 compact rows
    const int hbase = offsets[e] + mt * 128;
    #pragma unroll
    for (int mi = 0; mi < 4; ++mi)
        #pragma unroll
        for (int ni = 0; ni < 2; ++ni)
            #pragma unroll
            for (int r = 0; r < 4; ++r) {
                int rl = wr + mi * 16 + (l >> 4) * 4 + r;
                int sl = mt * 128 + rl;
                if (sl < cnt) {
                    float v1 = acc1[mi][ni][r];
                    v1 = v1 > 0.f ? v1 : 0.f;
                    float hv = v1 * acc3[mi][ni][r];
                    hbuf[(size_t)(hbase + rl) * FDIM + (n0 + wc + ni * 16 + lr)] =
                        (unsigned short)f2bf1(hv);
                }
            }
}

// ---------------------------------------------------------------- GEMM2
// out[t, n] += w * (h W2)[slot, n]. BM=128 x BN=64 x BK=64, K=8192.
__global__ __launch_bounds__(256, 2)
void moe_gemm2(const unsigned short* __restrict__ hbuf, const float* __restrict__ W2,
               const int* __restrict__ counts, const int* __restrict__ offsets,
               const int* __restrict__ tok_id, const float* __restrict__ tok_w,
               float* __restrict__ out) {
    const int nt = blockIdx.x, mt = blockIdx.y, e = blockIdx.z;
    const int cnt = counts[e];
    if (mt * 128 >= cnt) return;
    const int n0 = nt * 64;
    const int tid = threadIdx.x;

    __shared__ __align__(16) unsigned char sA[128 * 64 * 2];
    __shared__ __align__(16) unsigned char sB[64 * 64 * 2];

    // A staging from hbuf (bf16): 8 lanes/row x uint4; 4 row passes.
    // Wave instr = 8 rows x 128B contiguous (full bf16 row).
    const int ar0 = tid >> 3;          // 0..31
    const int ak8 = (tid & 7) * 8;     // bf16 index
    const unsigned short* aptr[4];
    #pragma unroll
    for (int p = 0; p < 4; ++p) {
        int row = offsets[e] + mt * 128 + ar0 + 32 * p;
        aptr[p] = hbuf + (size_t)row * FDIM + ak8;
    }
    const int kq4 = (tid >> 4) * 4;
    const int n4 = (tid & 15) * 4;
    const float* b2p = W2 + (size_t)e * ((size_t)FDIM * HDIM) + (size_t)kq4 * HDIM + n0 + n4;

    const int w = tid >> 6, l = tid & 63;
    const int wr = (w >> 1) * 64, wc = (w & 1) * 32;
    const int lr = l & 15, lk = (l >> 4) * 8;

    f32x4 acc[4][2];
    #pragma unroll
    for (int mi = 0; mi < 4; ++mi)
        #pragma unroll
        for (int ni = 0; ni < 2; ++ni) acc[mi][ni] = (f32x4)0.f;

    uint4 areg[4]; float4 br[4];
    #pragma unroll
    for (int p = 0; p < 4; ++p) areg[p] = *(const uint4*)(aptr[p]);
    #pragma unroll
    for (int r = 0; r < 4; ++r) br[r] = *(const float4*)(b2p + (size_t)r * HDIM);

    for (int kt = 0; kt < FDIM / 64; ++kt) {
        #pragma unroll
        for (int p = 0; p < 4; ++p)
            *(uint4*)&sA[A_OFF(ar0 + 32 * p, ak8)] = areg[p];
        {
            const float* f = (const float*)br;
            #pragma unroll
            for (int c = 0; c < 4; ++c) {
                uint2 q;
                q.x = cvtpk(f[c], f[4 + c]);
                q.y = cvtpk(f[8 + c], f[12 + c]);
                *(uint2*)&sB[B_OFF(n4 + c, kq4)] = q;
            }
        }
        __syncthreads();
        if (kt + 1 < FDIM / 64) {
            #pragma unroll
            for (int p = 0; p < 4; ++p)
                areg[p] = *(const uint4*)(aptr[p] + (kt + 1) * 64);
            #pragma unroll
            for (int r = 0; r < 4; ++r)
                br[r] = *(const float4*)(b2p + (size_t)((kt + 1) * 64 + r) * HDIM);
        }
        #pragma unroll
        for (int ks = 0; ks < 2; ++ks) {
            const int kk = ks * 32 + lk;
            short8 a[4];
            #pragma unroll
            for (int mi = 0; mi < 4; ++mi)
                a[mi] = *(const short8*)&sA[A_OFF(wr + mi * 16 + lr, kk)];
            #pragma unroll
            for (int ni = 0; ni < 2; ++ni) {
                short8 b = *(const short8*)&sB[B_OFF(wc + ni * 16 + lr, kk)];
                #pragma unroll
                for (int mi = 0; mi < 4; ++mi)
                    acc[mi][ni] = __builtin_amdgcn_mfma_f32_16x16x32_bf16(a[mi], b, acc[mi][ni], 0, 0, 0);
            }
        }
        __syncthreads();
    }
    // ---- epilogue: scaled scatter-add
    #pragma unroll
    for (int mi = 0; mi < 4; ++mi)
        #pragma unroll
        for (int ni = 0; ni < 2; ++ni)
            #pragma unroll
            for (int r = 0; r < 4; ++r) {
                int rl = wr + mi * 16 + (l >> 4) * 4 + r;
                int sl = mt * 128 + rl;
                if (sl < cnt) {
                    int tk = tok_id[e * MAXT + sl];
                    float wgt = tok_w[e * MAXT + sl];
                    atomicAdd(&out[(size_t)tk * HDIM + (n0 + wc + ni * 16 + lr)],
                              wgt * acc[mi][ni][r]);
                }
            }
}

// ---------------------------------------------------------------- launch
extern "C" void kernel_launch(void* const* d_in, const int* in_sizes, int n_in,
                              void* d_out, int out_size, void* d_ws, size_t ws_size,
                              hipStream_t stream) {
    const float* x  = (const float*)d_in[0];
    const float* Wg = (const float*)d_in[1];
    const float* W1 = (const float*)d_in[2];
    const float* W2 = (const float*)d_in[3];
    const float* W3 = (const float*)d_in[4];
    float* out = (float*)d_out;

    char* ws = (char*)d_ws;
    int*   counts  = (int*)(ws + 0);
    int*   offsets = (int*)(ws + 32);
    int*   tok_id  = (int*)(ws + 64);
    float* tok_w   = (float*)(ws + 64 + NEXP * MAXT * 4);
    unsigned short* hbuf = (unsigned short*)(ws + 65536);  // (1024+128) x 8192 bf16

    hipMemsetAsync(ws, 0, 64, stream);
    hipMemsetAsync(d_out, 0, (size_t)out_size * sizeof(float), stream);

    moe_router<<<NTOK, 64, 0, stream>>>(x, Wg, counts, tok_id, tok_w);
    moe_scan<<<1, 64, 0, stream>>>(counts, offsets);
    moe_gemm1<<<dim3(FDIM / 64, 4, NEXP), 256, 0, stream>>>(x, W1, W3, counts, offsets, tok_id, hbuf);
    moe_gemm2<<<dim3(HDIM / 64, 4, NEXP), 256, 0, stream>>>(hbuf, W2, counts, offsets, tok_id, tok_w, out);
}

// Round 3
// 481.119 us; speedup vs baseline: 2.1328x; 2.1328x over previous
//
#include <hip/hip_runtime.h>
#include <hip/hip_bf16.h>

// MoE block: H=2048, F=8192, E=8, top-2, T=512 tokens. All inputs fp32.
// Round 3: all global->LDS staging via global_load_lds (async DMA, no VGPR
// liveness). A-side bf16 (x pre-converted; hbuf already bf16) with m201-style
// source-pre-swizzle + swizzled ds_read_b128. B-side (weights) staged RAW fp32
// [k][n]-linear with k-octet source XOR; fragments = 8x ds_read_b32 (2-way
// conflict = free) + cvt_pk. Split-K=4 in gemm2 for occupancy.

#define HDIM 2048
#define FDIM 8192
#define NEXP 8
#define NTOK 512
#define MAXT 512

typedef __attribute__((ext_vector_type(8))) short short8;
typedef __attribute__((ext_vector_type(4))) float f32x4;
typedef unsigned int u32;
typedef unsigned short u16;

__device__ __forceinline__ unsigned cvtpk(float lo, float hi) {
    unsigned r;
    asm("v_cvt_pk_bf16_f32 %0, %1, %2" : "=v"(r) : "v"(lo), "v"(hi));
    return r;
}
__device__ __forceinline__ unsigned f2bf1(float f) {
    unsigned u = __builtin_bit_cast(unsigned, f);
    return (u + 0x7FFFu + ((u >> 16) & 1u)) >> 16;
}
__device__ __forceinline__ void gload16(const void* g, void* l) {
    __builtin_amdgcn_global_load_lds((const __attribute__((address_space(1))) u32*)g,
                                     (__attribute__((address_space(3))) u32*)l, 16, 0, 0);
}

// A tile (bf16 [128 rows][64 k]) byte offset, XOR-swizzled; matches the
// linear DMA layout with source chunk pre-XOR (chunk ^= row&7).
#define A_OFF(r, k) (((((r)*64) + (k)) * 2) ^ ((((r) & 7)) << 4))

// ---------------------------------------------------------------- router
__global__ void moe_router(const float* __restrict__ x, const float* __restrict__ Wg,
                           int* __restrict__ counts, int* __restrict__ tok_id,
                           float* __restrict__ tok_w) {
    const int t = blockIdx.x;
    const int lane = threadIdx.x;
    const float* xr = x + (size_t)t * HDIM;
    float acc[8];
    #pragma unroll
    for (int e = 0; e < 8; ++e) acc[e] = 0.f;
    #pragma unroll 4
    for (int i = 0; i < HDIM / 64; ++i) {
        int h = lane + i * 64;
        float xv = xr[h];
        const float4* wr = (const float4*)(Wg + (size_t)h * 8);
        float4 wa = wr[0], wb = wr[1];
        acc[0] += xv * wa.x; acc[1] += xv * wa.y; acc[2] += xv * wa.z; acc[3] += xv * wa.w;
        acc[4] += xv * wb.x; acc[5] += xv * wb.y; acc[6] += xv * wb.z; acc[7] += xv * wb.w;
    }
    #pragma unroll
    for (int off = 32; off >= 1; off >>= 1) {
        #pragma unroll
        for (int e = 0; e < 8; ++e) acc[e] += __shfl_xor(acc[e], off);
    }
    if (lane == 0) {
        int e0 = 0;
        #pragma unroll
        for (int e = 1; e < 8; ++e) if (acc[e] > acc[e0]) e0 = e;
        int e1 = (e0 == 0) ? 1 : 0;
        #pragma unroll
        for (int e = 0; e < 8; ++e) if (e != e0 && acc[e] > acc[e1]) e1 = e;
        float w0 = 1.f / (1.f + __expf(acc[e1] - acc[e0]));
        float w1 = 1.f - w0;
        int s0 = atomicAdd(&counts[e0], 1);
        tok_id[e0 * MAXT + s0] = t; tok_w[e0 * MAXT + s0] = w0;
        int s1 = atomicAdd(&counts[e1], 1);
        tok_id[e1 * MAXT + s1] = t; tok_w[e1 * MAXT + s1] = w1;
    }
}

__global__ void moe_scan(const int* __restrict__ counts, int* __restrict__ offsets) {
    if (threadIdx.x == 0) {
        int a = 0;
        for (int e = 0; e < NEXP; ++e) { offsets[e] = a; a += counts[e]; }
    }
}

// ------------------------------------------------------------- x -> bf16
__global__ void moe_xcvt(const float* __restrict__ x, u16* __restrict__ xbf) {
    const int i = (blockIdx.x * 256 + threadIdx.x) * 8;  // 512 blocks cover 1M
    float4 a = *(const float4*)(x + i);
    float4 b = *(const float4*)(x + i + 4);
    uint4 q;
    q.x = cvtpk(a.x, a.y); q.y = cvtpk(a.z, a.w);
    q.z = cvtpk(b.x, b.y); q.w = cvtpk(b.z, b.w);
    *(uint4*)(xbf + i) = q;
}

// B-fragment build: weights are fp32 in LDS as [k][64 n] with dword slot
// n' = n ^ (((k>>3)&1)<<4). 8x ds_read_b32 (stride 256B) + 4 cvt_pk.
__device__ __forceinline__ short8 bfrag(const float* sB, int kbase, int nsw) {
    const float* p = sB + kbase * 64 + nsw;
    float f[8];
    #pragma unroll
    for (int j = 0; j < 8; ++j) f[j] = p[j * 64];
    uint4 q;
    q.x = cvtpk(f[0], f[1]); q.y = cvtpk(f[2], f[3]);
    q.z = cvtpk(f[4], f[5]); q.w = cvtpk(f[6], f[7]);
    return __builtin_bit_cast(short8, q);
}

// ---------------------------------------------------------------- GEMM1
// h[slot,n] = relu(x W1) * (x W3), bf16 out. BM=128 BN=64 BK=64, waves 2x2.
__global__ __launch_bounds__(256, 3)
void moe_gemm1(const u16* __restrict__ xbf, const float* __restrict__ W1,
               const float* __restrict__ W3, const int* __restrict__ counts,
               const int* __restrict__ offsets, const int* __restrict__ tok_id,
               u16* __restrict__ hbuf) {
    const int nt = blockIdx.x, mt = blockIdx.y, e = blockIdx.z;
    const int cnt = counts[e];
    if (mt * 128 >= cnt) return;
    const int n0 = nt * 64;
    const int tid = threadIdx.x;
    const int w = tid >> 6, l = tid & 63;

    __shared__ __align__(16) unsigned char sA[128 * 64 * 2];   // bf16 swizzled
    __shared__ __align__(16) float sB1[64 * 64];               // fp32 [k][n']
    __shared__ __align__(16) float sB3[64 * 64];

    // ---- A staging map (DMA): lane covers row = w*32+p*8+(l>>3), chunk l&7.
    const int ar = (l >> 3), ac = l & 7;
    const u16* asrc[4];
    #pragma unroll
    for (int p = 0; p < 4; ++p) {
        int row = w * 32 + p * 8 + ar;
        int slot = mt * 128 + row;
        int tok = tok_id[e * MAXT + (slot < cnt ? slot : cnt - 1)];
        asrc[p] = xbf + (size_t)tok * HDIM + (ac ^ (row & 7)) * 8;
    }
    // ---- B staging map: lane covers krow = w*16+p*4+(l>>4), chunk c4 = l&15;
    // source chunk = c4 ^ (((krow>>3)&1)<<2).
    const int kr = (l >> 4), c4 = l & 15;
    const size_t wstride = (size_t)HDIM * FDIM;
    size_t bsrc[4];
    #pragma unroll
    for (int p = 0; p < 4; ++p) {
        int krow = w * 16 + p * 4 + kr;
        bsrc[p] = (size_t)e * wstride + (size_t)krow * FDIM + n0 +
                  (size_t)((c4 ^ (((krow >> 3) & 1) << 2)) * 4);
    }

    const int wr = (w >> 1) * 64, wc = (w & 1) * 32;
    const int lr = l & 15, lg = l >> 4;
    const int lk = lg * 8;
    const int g1 = lg & 1;

    f32x4 acc1[4][2], acc3[4][2];
    #pragma unroll
    for (int mi = 0; mi < 4; ++mi)
        #pragma unroll
        for (int ni = 0; ni < 2; ++ni) { acc1[mi][ni] = (f32x4)0.f; acc3[mi][ni] = (f32x4)0.f; }

    for (int kt = 0; kt < HDIM / 64; ++kt) {
        // ---- stage (async DMA, no VGPRs)
        #pragma unroll
        for (int p = 0; p < 4; ++p) {
            gload16(asrc[p] + kt * 64, &sA[(w * 32 + p * 8) * 128]);
            gload16(W1 + bsrc[p] + (size_t)kt * 64 * FDIM, &sB1[(w * 16 + p * 4) * 64]);
            gload16(W3 + bsrc[p] + (size_t)kt * 64 * FDIM, &sB3[(w * 16 + p * 4) * 64]);
        }
        __syncthreads();   // compiler drains vmcnt(0) before barrier
        // ---- compute
        #pragma unroll
        for (int ks = 0; ks < 2; ++ks) {
            const int kk = ks * 32 + lk;
            short8 a[4];
            #pragma unroll
            for (int mi = 0; mi < 4; ++mi)
                a[mi] = *(const short8*)&sA[A_OFF(wr + mi * 16 + lr, kk)];
            #pragma unroll
            for (int ni = 0; ni < 2; ++ni) {
                const int nsw = (wc + ni * 16 + lr) ^ (g1 << 4);
                short8 b1 = bfrag(sB1, kk, nsw);
                short8 b3 = bfrag(sB3, kk, nsw);
                #pragma unroll
                for (int mi = 0; mi < 4; ++mi) {
                    acc1[mi][ni] = __builtin_amdgcn_mfma_f32_16x16x32_bf16(a[mi], b1, acc1[mi][ni], 0, 0, 0);
                    acc3[mi][ni] = __builtin_amdgcn_mfma_f32_16x16x32_bf16(a[mi], b3, acc3[mi][ni], 0, 0, 0);
                }
            }
        }
        __syncthreads();   // all reads done before next stage overwrites
    }
    // ---- epilogue: h = relu(h1)*h3 -> bf16 compact rows
    const int hbase = offsets[e] + mt * 128;
    #pragma unroll
    for (int mi = 0; mi < 4; ++mi)
        #pragma unroll
        for (int ni = 0; ni < 2; ++ni)
            #pragma unroll
            for (int r = 0; r < 4; ++r) {
                int rl = wr + mi * 16 + (l >> 4) * 4 + r;
                int sl = mt * 128 + rl;
                if (sl < cnt) {
                    float v1 = acc1[mi][ni][r];
                    v1 = v1 > 0.f ? v1 : 0.f;
                    float hv = v1 * acc3[mi][ni][r];
                    hbuf[(size_t)(hbase + rl) * FDIM + (n0 + wc + ni * 16 + lr)] =
                        (u16)f2bf1(hv);
                }
            }
}

// ---------------------------------------------------------------- GEMM2
// out[t,n] += w * (h W2). BM=128 BN=64 BK=64, split-K x4 (2048 each).
__global__ __launch_bounds__(256, 4)
void moe_gemm2(const u16* __restrict__ hbuf, const float* __restrict__ W2,
               const int* __restrict__ counts, const int* __restrict__ offsets,
               const int* __restrict__ tok_id, const float* __restrict__ tok_w,
               float* __restrict__ out) {
    const int nt = blockIdx.x, e = blockIdx.z;
    const int mt = blockIdx.y & 3, ksp = blockIdx.y >> 2;
    const int cnt = counts[e];
    if (mt * 128 >= cnt) return;
    const int n0 = nt * 64;
    const int tid = threadIdx.x;
    const int w = tid >> 6, l = tid & 63;

    __shared__ __align__(16) unsigned char sA[128 * 64 * 2];
    __shared__ __align__(16) float sB[64 * 64];

    const int ar = (l >> 3), ac = l & 7;
    const u16* asrc[4];
    #pragma unroll
    for (int p = 0; p < 4; ++p) {
        int row = w * 32 + p * 8 + ar;
        int hrow = offsets[e] + mt * 128 + row;  // hbuf padded; tail rows masked in epilogue
        asrc[p] = hbuf + (size_t)hrow * FDIM + ksp * 2048 + (ac ^ (row & 7)) * 8;
    }
    const int kr = (l >> 4), c4 = l & 15;
    size_t bsrc[4];
    #pragma unroll
    for (int p = 0; p < 4; ++p) {
        int krow = w * 16 + p * 4 + kr;
        bsrc[p] = (size_t)e * ((size_t)FDIM * HDIM) + (size_t)(ksp * 2048 + krow) * HDIM +
                  n0 + (size_t)((c4 ^ (((krow >> 3) & 1) << 2)) * 4);
    }

    const int wr = (w >> 1) * 64, wc = (w & 1) * 32;
    const int lr = l & 15, lg = l >> 4;
    const int lk = lg * 8;
    const int g1 = lg & 1;

    f32x4 acc[4][2];
    #pragma unroll
    for (int mi = 0; mi < 4; ++mi)
        #pragma unroll
        for (int ni = 0; ni < 2; ++ni) acc[mi][ni] = (f32x4)0.f;

    for (int kt = 0; kt < 32; ++kt) {
        #pragma unroll
        for (int p = 0; p < 4; ++p) {
            gload16(asrc[p] + kt * 64, &sA[(w * 32 + p * 8) * 128]);
            gload16(W2 + bsrc[p] + (size_t)kt * 64 * HDIM, &sB[(w * 16 + p * 4) * 64]);
        }
        __syncthreads();
        #pragma unroll
        for (int ks = 0; ks < 2; ++ks) {
            const int kk = ks * 32 + lk;
            short8 a[4];
            #pragma unroll
            for (int mi = 0; mi < 4; ++mi)
                a[mi] = *(const short8*)&sA[A_OFF(wr + mi * 16 + lr, kk)];
            #pragma unroll
            for (int ni = 0; ni < 2; ++ni) {
                const int nsw = (wc + ni * 16 + lr) ^ (g1 << 4);
                short8 b = bfrag(sB, kk, nsw);
                #pragma unroll
                for (int mi = 0; mi < 4; ++mi)
                    acc[mi][ni] = __builtin_amdgcn_mfma_f32_16x16x32_bf16(a[mi], b, acc[mi][ni], 0, 0, 0);
            }
        }
        __syncthreads();
    }
    // ---- epilogue: scaled partial scatter-add (4 splits x 2 experts per elem)
    #pragma unroll
    for (int mi = 0; mi < 4; ++mi)
        #pragma unroll
        for (int ni = 0; ni < 2; ++ni)
            #pragma unroll
            for (int r = 0; r < 4; ++r) {
                int rl = wr + mi * 16 + (l >> 4) * 4 + r;
                int sl = mt * 128 + rl;
                if (sl < cnt) {
                    int tk = tok_id[e * MAXT + sl];
                    float wgt = tok_w[e * MAXT + sl];
                    atomicAdd(&out[(size_t)tk * HDIM + (n0 + wc + ni * 16 + lr)],
                              wgt * acc[mi][ni][r]);
                }
            }
}

// ---------------------------------------------------------------- launch
extern "C" void kernel_launch(void* const* d_in, const int* in_sizes, int n_in,
                              void* d_out, int out_size, void* d_ws, size_t ws_size,
                              hipStream_t stream) {
    const float* x  = (const float*)d_in[0];
    const float* Wg = (const float*)d_in[1];
    const float* W1 = (const float*)d_in[2];
    const float* W2 = (const float*)d_in[3];
    const float* W3 = (const float*)d_in[4];
    float* out = (float*)d_out;

    char* ws = (char*)d_ws;
    int*   counts  = (int*)(ws + 0);
    int*   offsets = (int*)(ws + 32);
    int*   tok_id  = (int*)(ws + 64);
    float* tok_w   = (float*)(ws + 64 + NEXP * MAXT * 4);
    u16*   xbf     = (u16*)(ws + 65536);                       // 512x2048 bf16 = 2MB
    u16*   hbuf    = (u16*)(ws + 65536 + (size_t)NTOK * HDIM * 2);  // (1024+128)x8192 bf16

    hipMemsetAsync(ws, 0, 64, stream);
    hipMemsetAsync(d_out, 0, (size_t)out_size * sizeof(float), stream);

    moe_router<<<NTOK, 64, 0, stream>>>(x, Wg, counts, tok_id, tok_w);
    moe_scan<<<1, 64, 0, stream>>>(counts, offsets);
    moe_xcvt<<<NTOK * HDIM / (256 * 8), 256, 0, stream>>>(x, xbf);
    moe_gemm1<<<dim3(FDIM / 64, 4, NEXP), 256, 0, stream>>>(xbf, W1, W3, counts, offsets, tok_id, hbuf);
    moe_gemm2<<<dim3(HDIM / 64, 16, NEXP), 256, 0, stream>>>(hbuf, W2, counts, offsets, tok_id, tok_w, out);
}